// Round 1
// baseline (120.338 us; speedup 1.0000x reference)
//
#include <hip/hip_runtime.h>

// Problem constants (from reference)
#define W_DIM 8192
#define MAXP 4096
#define MAXE 2048
#define NB 16

// Kernel 1: bulk copy req_to_token -> out, float4-vectorized, grid-stride.
__global__ void copy_kernel(const float4* __restrict__ in,
                            float4* __restrict__ out, long n4) {
    long i = (long)blockIdx.x * blockDim.x + threadIdx.x;
    long stride = (long)gridDim.x * blockDim.x;
    for (; i < n4; i += stride) {
        out[i] = in[i];
    }
}

// Kernel 2: overwrite the first seq_lens[b] elements of the 16 selected rows.
// One block per batch entry; positions >= seq keep the copied "existing" vals.
__global__ void row_update_kernel(float* __restrict__ out,
                                  const float* __restrict__ prefix,   // [NB][MAXP]
                                  const float* __restrict__ cache,    // [NB*MAXE]
                                  const int* __restrict__ pool_idx,   // [NB]
                                  const int* __restrict__ pre_len,    // [NB]
                                  const int* __restrict__ seq_len,    // [NB]
                                  const int* __restrict__ ext_len) {  // [NB]
    int b = blockIdx.x;
    int row = pool_idx[b];
    int pre = pre_len[b];
    int seq = seq_len[b];
    // exclusive prefix sum of extend_lens (16 entries, trivially cheap, L1-hot)
    int start = 0;
    for (int j = 0; j < b; ++j) start += ext_len[j];

    float* dst = out + (long)row * W_DIM;
    for (int pos = threadIdx.x; pos < seq; pos += blockDim.x) {
        float v = (pos < pre) ? prefix[b * MAXP + pos]
                              : cache[start + (pos - pre)];
        dst[pos] = v;
    }
}

extern "C" void kernel_launch(void* const* d_in, const int* in_sizes, int n_in,
                              void* d_out, int out_size, void* d_ws, size_t ws_size,
                              hipStream_t stream) {
    const float* req_to_token = (const float*)d_in[0];  // [POOL*W]
    const float* prefix       = (const float*)d_in[1];  // [NB*MAXP]
    const float* cache        = (const float*)d_in[2];  // [NB*MAXE]
    const int*   pool_idx     = (const int*)d_in[3];    // [NB]
    const int*   pre_len      = (const int*)d_in[4];    // [NB]
    const int*   seq_len      = (const int*)d_in[5];    // [NB]
    const int*   ext_len      = (const int*)d_in[6];    // [NB]
    float* out = (float*)d_out;

    long n = (long)in_sizes[0];   // POOL * W = 64M floats, divisible by 4
    long n4 = n / 4;

    copy_kernel<<<2048, 256, 0, stream>>>(
        (const float4*)req_to_token, (float4*)out, n4);
    row_update_kernel<<<NB, 256, 0, stream>>>(
        out, prefix, cache, pool_idx, pre_len, seq_len, ext_len);
}

// Round 3
// 89.142 us; speedup vs baseline: 1.3500x; 1.3500x over previous
//
#include <hip/hip_runtime.h>

// Problem constants (from reference)
#define W_DIM 8192
#define MAXP 4096
#define MAXE 2048
#define NB 16

// Native vector type — accepted by __builtin_nontemporal_load/store
// (HIP_vector_type<float,4> is a struct and is rejected).
typedef float f32x4 __attribute__((ext_vector_type(4)));

// One block per pool row. Non-special rows: pure streaming copy (nt hints).
// Special rows (the 16 in req_pool_indices): overlay prefix/cache values.
// Every output element written exactly once -> no inter-kernel ordering needed.
__global__ void fused_row_kernel(const f32x4* __restrict__ in,
                                 f32x4* __restrict__ out,
                                 const float* __restrict__ prefix,   // [NB][MAXP]
                                 const float* __restrict__ cache,    // [NB*MAXE]
                                 const int* __restrict__ pool_idx,   // [NB]
                                 const int* __restrict__ pre_len,    // [NB]
                                 const int* __restrict__ seq_len,    // [NB]
                                 const int* __restrict__ ext_len) {  // [NB]
    const int row = blockIdx.x;
    const long base4 = (long)row * (W_DIM / 4);

    // Block-uniform special-row detection (16 scalar loads, L1-hot).
    int b = -1;
    #pragma unroll
    for (int j = 0; j < NB; ++j) {
        if (pool_idx[j] == row) b = j;
    }

    if (b < 0) {
        // Fast path: 2048 float4 per row / 256 threads = 8 iterations.
        #pragma unroll
        for (int k = 0; k < 8; ++k) {
            long i = base4 + k * 256 + threadIdx.x;
            f32x4 v = __builtin_nontemporal_load(&in[i]);
            __builtin_nontemporal_store(v, &out[i]);
        }
    } else {
        const int pre = pre_len[b];
        const int seq = seq_len[b];
        int start = 0;
        for (int j = 0; j < b; ++j) start += ext_len[j];

        for (int p4 = threadIdx.x; p4 < W_DIM / 4; p4 += blockDim.x) {
            f32x4 v = in[base4 + p4];
            const int pos0 = p4 * 4;
            #pragma unroll
            for (int c = 0; c < 4; ++c) {
                const int pos = pos0 + c;
                if (pos < pre) {
                    v[c] = prefix[b * MAXP + pos];
                } else if (pos < seq) {
                    v[c] = cache[start + (pos - pre)];
                }
            }
            out[base4 + p4] = v;
        }
    }
}

extern "C" void kernel_launch(void* const* d_in, const int* in_sizes, int n_in,
                              void* d_out, int out_size, void* d_ws, size_t ws_size,
                              hipStream_t stream) {
    const float* req_to_token = (const float*)d_in[0];  // [POOL*W]
    const float* prefix       = (const float*)d_in[1];  // [NB*MAXP]
    const float* cache        = (const float*)d_in[2];  // [NB*MAXE]
    const int*   pool_idx     = (const int*)d_in[3];    // [NB]
    const int*   pre_len      = (const int*)d_in[4];    // [NB]
    const int*   seq_len      = (const int*)d_in[5];    // [NB]
    const int*   ext_len      = (const int*)d_in[6];    // [NB]
    float* out = (float*)d_out;

    const int pool_rows = in_sizes[0] / W_DIM;  // 8192

    fused_row_kernel<<<pool_rows, 256, 0, stream>>>(
        (const f32x4*)req_to_token, (f32x4*)out,
        prefix, cache, pool_idx, pre_len, seq_len, ext_len);
}